// Round 4
// baseline (269.665 us; speedup 1.0000x reference)
//
#include <hip/hip_runtime.h>
#include <math.h>

// Problem constants (fixed by reference: B=8, C=3, H=W=1024)
constexpr int BC = 24;     // B*C point-set pairs
constexpr int N  = 1024;   // points per set
constexpr int D  = 1024;   // point dimension
constexpr int TILE = 128;  // 128x128 output tile per block
constexpr int SKF = 40;    // fallback kernel LDS stride (bf16)

typedef short short8 __attribute__((ext_vector_type(8)));
typedef float f32x4  __attribute__((ext_vector_type(4)));
typedef long lng2    __attribute__((ext_vector_type(2)));   // two i64 fp8 fragments

#define FINF 3.402823466e+38f

// ---- Swizzled fp8 layout (used identically by prep-write and tile-read) ----
// Super-tile ST = (bc, R = row>>4, Kp = k>>6): 16 rows x 64 k = 1024 fp8 = 1 KB.
// Within: r16 = row&15, dose = (k>>5)&1, quad = (k>>3)&3, j = k&7.
// lane = r16 | (quad<<4); flat byte = ST*1024 + lane*16 + dose*8 + j.
// Tile kernel reads a fragment pair as one coalesced 1-KB global_load_dwordx4.
//
// R2 lesson (measured): permutation on the STORE side inflates WRITE_SIZE
// 52->86 MB (partial-line writebacks) -> permutation must not scatter stores.
// R3 lesson (measured): gather-READ prep is latency-bound at 1.8 TB/s, 7%
// VALU, 61% occ (4 loads in flight/wave, half-covered sectors). Fix: do the
// transpose in LDS -> BOTH global sides contiguous, 16 loads in flight/wave.

// Pack two fp32 -> two bf16 (fallback path only). HW-verified R2-R5.
__device__ inline unsigned pk_bf16(float a, float b) {
    unsigned ua = __float_as_uint(a) + 0x8000u;
    unsigned ub = __float_as_uint(b) + 0x8000u;
    return __builtin_amdgcn_perm(ub, ua, 0x07060302);
}

// 4 floats -> one 32-bit word of 4 fp8-e4m3 (OCP on gfx950), RTNE.
__device__ inline int pk_fp8x4(float a, float b, float c, float d) {
    int w = __builtin_amdgcn_cvt_pk_fp8_f32(a, b, 0, false);   // bytes 0,1
    w = __builtin_amdgcn_cvt_pk_fp8_f32(c, d, w, true);        // bytes 2,3
    return w;
}

// ============================ FAST PATH ============================
// ---- Kernel 1h: LDS-transpose prep (fp32 -> swizzled fp8) + exact norms ----
// Block = one (tensor, bc, R) 16-row group: 64 KB fp32 in, 16 KB fp8 out.
// 3072 blocks x 256 threads. Wave w reads rows w*4..w*4+3 as contiguous 1-KB
// wave loads (16 in flight), converts, writes LDS row-major (bank-perfect),
// reduces exact fp32 row norms in-register (plain store, no atomics, no
// memset needed). After barrier: 4 rounds of 2x ds_read_b64 (2-way = free)
// -> contiguous 1-KB/wave swizzled stores. Consumer layout unchanged.
__global__ __launch_bounds__(256) void prep_kernel(const float* __restrict__ X,
                                                   const float* __restrict__ Y,
                                                   unsigned char* __restrict__ Xf8,
                                                   unsigned char* __restrict__ Yf8,
                                                   float* __restrict__ xn,
                                                   float* __restrict__ yn) {
    __shared__ unsigned lds[16 * 260];   // 16 rows x 256 dwords, +4 dword pad
    int wave = threadIdx.x >> 6, lane = threadIdx.x & 63;
    int gid = blockIdx.x;                // 0..3071
    bool isY = gid >= 1536;
    int g = isY ? gid - 1536 : gid;
    int bc = g >> 6, R = g & 63;

    const float* __restrict__ src = (isY ? Y : X)
        + ((size_t)bc * N + (size_t)R * 16 + wave * 4) * D + lane * 4;
    unsigned char* __restrict__ dst = (isY ? Yf8 : Xf8)
        + (size_t)(bc * 64 + R) * 16384;           // ST base (16 STs x 1 KB)
    float* __restrict__ nrm = (isY ? yn : xn) + bc * N + R * 16 + wave * 4;

    // Load phase: 16 contiguous 1-KB wave loads, all in flight.
    float4 v[4][4];                                // [row i][seg q]
    #pragma unroll
    for (int i = 0; i < 4; i++)
        #pragma unroll
        for (int q = 0; q < 4; q++)
            v[i][q] = *(const float4*)(src + (size_t)i * D + q * 256);

    // Convert + LDS (row-major: dword idx = r*260 + k/4) + exact row norms.
    float4 ns;
    float* nsp = (float*)&ns;
    #pragma unroll
    for (int i = 0; i < 4; i++) {
        int r = wave * 4 + i;
        float s = 0.f;
        #pragma unroll
        for (int q = 0; q < 4; q++) {
            float4 c = v[i][q];
            lds[r * 260 + q * 64 + lane] = (unsigned)pk_fp8x4(c.x, c.y, c.z, c.w);
            s += c.x * c.x + c.y * c.y + c.z * c.z + c.w * c.w;
        }
        #pragma unroll
        for (int m = 1; m < 64; m <<= 1) s += __shfl_xor(s, m, 64);
        nsp[i] = s;
    }
    if (lane == 0) *(float4*)nrm = ns;             // rows wave*4..+3, aligned

    __syncthreads();

    // Store phase: swizzled gather from LDS, contiguous 1-KB wave stores.
    // Store lane l covers ST bytes r16*16 + quad*256 (+0..15):
    //   dose0 j0..7 -> LDS dwords r16*260 + Kp*16 + quad*2 + {0,1}
    //   dose1 j0..7 -> same + 8. Banks: (r16*4 + quad*2)%32 -> 2-way (free).
    int r16 = lane & 15, quad = lane >> 4;
    #pragma unroll
    for (int gr = 0; gr < 4; gr++) {
        int Kp = gr * 4 + wave;
        int di = r16 * 260 + Kp * 16 + quad * 2;
        uint2 d0 = *(const uint2*)&lds[di];
        uint2 d1 = *(const uint2*)&lds[di + 8];
        uint4 w4 = make_uint4(d0.x, d0.y, d1.x, d1.y);
        *(uint4*)(dst + Kp * 1024 + quad * 256 + r16 * 16) = w4;
    }
}

// ---- Kernel 2g: zero-LDS fp8 MFMA tile kernel + XCD-chunked block swizzle ----
// (R3: swizzle measured ~neutral (+2 us total) but harmless; kept.)
__global__ __launch_bounds__(256, 3) void tile_f8_kernel(const unsigned char* __restrict__ Xf8,
                                                         const unsigned char* __restrict__ Yf8,
                                                         const float* __restrict__ xn,
                                                         const float* __restrict__ yn,
                                                         unsigned* __restrict__ rowmin,
                                                         unsigned* __restrict__ colmin) {
    int raw = blockIdx.x;             // HW round-robins raw id across 8 XCDs
    int id = (raw & 7) * 192 + (raw >> 3);   // XCD-chunked logical tile id
    int bc = id >> 6;
    int tn = (id >> 3) & 7, tm = id & 7;

    int wave = threadIdx.x >> 6, lane = threadIdx.x & 63;
    int wr = wave >> 1, wc = wave & 1;      // wave tile: rows wr*64, cols wc*64
    int quad = lane >> 4, tx = lane & 15;

    const unsigned char* Xb = Xf8 + (size_t)bc * 1024 * 1024;   // 1024 STs x 1 KB per bc
    const unsigned char* Yb = Yf8 + (size_t)bc * 1024 * 1024;
    // A STs: R = tn*8 + wr*4 + mi (mi stride = 16 STs = 16 KB); Kp stride = 1 KB.
    const unsigned char* ax = Xb + (size_t)(tn * 8 + wr * 4) * 16 * 1024 + lane * 16;
    const unsigned char* by = Yb + (size_t)(tm * 8 + wc * 4) * 16 * 1024 + lane * 16;

    f32x4 acc[4][4];
    #pragma unroll
    for (int i = 0; i < 4; i++)
        #pragma unroll
        for (int j = 0; j < 4; j++) acc[i][j] = (f32x4)0.f;

    // 2-deep register pipeline over 16 Kp super-doses (2 MFMA doses each).
    lng2 a[2][4], b[2][4];
    #pragma unroll
    for (int mi = 0; mi < 4; mi++) {
        a[0][mi] = *(const lng2*)(ax + mi * 16384);
        b[0][mi] = *(const lng2*)(by + mi * 16384);
    }
    #pragma unroll
    for (int Kp = 0; Kp < 16; Kp++) {
        int cur = Kp & 1, nxt = cur ^ 1;
        if (Kp < 15) {
            #pragma unroll
            for (int mi = 0; mi < 4; mi++) {
                a[nxt][mi] = *(const lng2*)(ax + mi * 16384 + (Kp + 1) * 1024);
                b[nxt][mi] = *(const lng2*)(by + mi * 16384 + (Kp + 1) * 1024);
            }
        }
        #pragma unroll
        for (int mi = 0; mi < 4; mi++)
            #pragma unroll
            for (int mj = 0; mj < 4; mj++)
                acc[mi][mj] = __builtin_amdgcn_mfma_f32_16x16x32_fp8_fp8(a[cur][mi].x, b[cur][mj].x, acc[mi][mj], 0, 0, 0);
        #pragma unroll
        for (int mi = 0; mi < 4; mi++)
            #pragma unroll
            for (int mj = 0; mj < 4; mj++)
                acc[mi][mj] = __builtin_amdgcn_mfma_f32_16x16x32_fp8_fp8(a[cur][mi].y, b[cur][mj].y, acc[mi][mj], 0, 0, 0);
    }

    // Epilogue. D-layout (shape-determined, dtype-independent): row = quad*4 + r, col = tx.
    int rbase = bc * N + tn * TILE + wr * 64;
    int cbase = bc * N + tm * TILE + wc * 64;
    float xnr[4][4], ynr[4];
    #pragma unroll
    for (int mi = 0; mi < 4; mi++)
        #pragma unroll
        for (int r = 0; r < 4; r++) xnr[mi][r] = xn[rbase + mi * 16 + quad * 4 + r];
    #pragma unroll
    for (int mj = 0; mj < 4; mj++) ynr[mj] = yn[cbase + mj * 16 + tx];

    float rmin[4][4], cmin[4];
    #pragma unroll
    for (int mi = 0; mi < 4; mi++)
        #pragma unroll
        for (int r = 0; r < 4; r++) rmin[mi][r] = FINF;
    #pragma unroll
    for (int mj = 0; mj < 4; mj++) cmin[mj] = FINF;

    #pragma unroll
    for (int mi = 0; mi < 4; mi++)
        #pragma unroll
        for (int mj = 0; mj < 4; mj++)
            #pragma unroll
            for (int r = 0; r < 4; r++) {
                float d2 = fmaxf(xnr[mi][r] + ynr[mj] - 2.f * acc[mi][mj][r], 0.f);
                rmin[mi][r] = fminf(rmin[mi][r], d2);
                cmin[mj]    = fminf(cmin[mj], d2);
            }

    #pragma unroll
    for (int m = 1; m < 16; m <<= 1)
        #pragma unroll
        for (int mi = 0; mi < 4; mi++)
            #pragma unroll
            for (int r = 0; r < 4; r++)
                rmin[mi][r] = fminf(rmin[mi][r], __shfl_xor(rmin[mi][r], m, 64));
    if (tx == 0) {
        #pragma unroll
        for (int mi = 0; mi < 4; mi++)
            #pragma unroll
            for (int r = 0; r < 4; r++)
                atomicMin(&rowmin[rbase + mi * 16 + quad * 4 + r], __float_as_uint(rmin[mi][r]));
    }
    #pragma unroll
    for (int m = 16; m < 64; m <<= 1)
        #pragma unroll
        for (int mj = 0; mj < 4; mj++)
            cmin[mj] = fminf(cmin[mj], __shfl_xor(cmin[mj], m, 64));
    if (quad == 0) {
        #pragma unroll
        for (int mj = 0; mj < 4; mj++)
            atomicMin(&colmin[cbase + mj * 16 + tx], __float_as_uint(cmin[mj]));
    }
}

// ============================ FALLBACK PATH (R2, proven) ============================
__global__ __launch_bounds__(256) void norms_kernel(const float* __restrict__ X,
                                                    const float* __restrict__ Y,
                                                    float* __restrict__ xn,
                                                    float* __restrict__ yn) {
    int w = threadIdx.x >> 6, lane = threadIdx.x & 63;
    long rid = (long)blockIdx.x * 4 + w;
    bool isY = rid >= (long)BC * N;
    long row = isY ? rid - (long)BC * N : rid;
    const float* src = (isY ? Y : X) + row * D;
    float s = 0.f;
    #pragma unroll
    for (int q = 0; q < 4; q++) {
        float4 v = ((const float4*)src)[lane + q * 64];
        s += v.x * v.x + v.y * v.y + v.z * v.z + v.w * v.w;
    }
    #pragma unroll
    for (int m = 1; m < 64; m <<= 1) s += __shfl_xor(s, m, 64);
    if (lane == 0) (isY ? yn : xn)[row] = s;
}

__global__ __launch_bounds__(256) void tile_conv_kernel(const float* __restrict__ X,
                                                        const float* __restrict__ Y,
                                                        const float* __restrict__ xn,
                                                        const float* __restrict__ yn,
                                                        unsigned* __restrict__ rowmin,
                                                        unsigned* __restrict__ colmin) {
    __shared__ unsigned short Xs[TILE * SKF];
    __shared__ unsigned short Ys[TILE * SKF];
    int bc = blockIdx.z, tn = blockIdx.y, tm = blockIdx.x;
    const float* Xb = X + ((size_t)bc * N + (size_t)tn * TILE) * D;
    const float* Yb = Y + ((size_t)bc * N + (size_t)tm * TILE) * D;

    int t = threadIdx.x;
    int srow = t >> 3, sq = t & 7;
    int wave = t >> 6, lane = t & 63;
    int wr = wave >> 1, wc = wave & 1;
    int quad = lane >> 4, tx = lane & 15;

    f32x4 acc[4][4];
    #pragma unroll
    for (int i = 0; i < 4; i++)
        #pragma unroll
        for (int j = 0; j < 4; j++) acc[i][j] = (f32x4)0.f;

    float4 xv[4], yv[4];
    #pragma unroll
    for (int i = 0; i < 4; i++) {
        xv[i] = *(const float4*)(Xb + (size_t)(srow + i * 32) * D + sq * 4);
        yv[i] = *(const float4*)(Yb + (size_t)(srow + i * 32) * D + sq * 4);
    }

    for (int k0 = 0; k0 < D; k0 += 32) {
        __syncthreads();
        #pragma unroll
        for (int i = 0; i < 4; i++) {
            uint2 px; px.x = pk_bf16(xv[i].x, xv[i].y); px.y = pk_bf16(xv[i].z, xv[i].w);
            *(uint2*)&Xs[(srow + i * 32) * SKF + sq * 4] = px;
            uint2 py; py.x = pk_bf16(yv[i].x, yv[i].y); py.y = pk_bf16(yv[i].z, yv[i].w);
            *(uint2*)&Ys[(srow + i * 32) * SKF + sq * 4] = py;
        }
        __syncthreads();
        if (k0 + 32 < D) {
            #pragma unroll
            for (int i = 0; i < 4; i++) {
                xv[i] = *(const float4*)(Xb + (size_t)(srow + i * 32) * D + k0 + 32 + sq * 4);
                yv[i] = *(const float4*)(Yb + (size_t)(srow + i * 32) * D + k0 + 32 + sq * 4);
            }
        }
        short8 af[4], bg[4];
        #pragma unroll
        for (int mi = 0; mi < 4; mi++)
            af[mi] = *(const short8*)&Xs[(wr * 64 + mi * 16 + tx) * SKF + quad * 8];
        #pragma unroll
        for (int mj = 0; mj < 4; mj++)
            bg[mj] = *(const short8*)&Ys[(wc * 64 + mj * 16 + tx) * SKF + quad * 8];
        #pragma unroll
        for (int mi = 0; mi < 4; mi++)
            #pragma unroll
            for (int mj = 0; mj < 4; mj++)
                acc[mi][mj] = __builtin_amdgcn_mfma_f32_16x16x32_bf16(af[mi], bg[mj], acc[mi][mj], 0, 0, 0);
    }

    int rbase = bc * N + tn * TILE + wr * 64;
    int cbase = bc * N + tm * TILE + wc * 64;
    float xnr[4][4], ynr[4];
    #pragma unroll
    for (int mi = 0; mi < 4; mi++)
        #pragma unroll
        for (int r = 0; r < 4; r++) xnr[mi][r] = xn[rbase + mi * 16 + quad * 4 + r];
    #pragma unroll
    for (int mj = 0; mj < 4; mj++) ynr[mj] = yn[cbase + mj * 16 + tx];

    float rmin[4][4], cmin[4];
    #pragma unroll
    for (int mi = 0; mi < 4; mi++)
        #pragma unroll
        for (int r = 0; r < 4; r++) rmin[mi][r] = FINF;
    #pragma unroll
    for (int mj = 0; mj < 4; mj++) cmin[mj] = FINF;

    #pragma unroll
    for (int mi = 0; mi < 4; mi++)
        #pragma unroll
        for (int mj = 0; mj < 4; mj++)
            #pragma unroll
            for (int r = 0; r < 4; r++) {
                float d2 = fmaxf(xnr[mi][r] + ynr[mj] - 2.f * acc[mi][mj][r], 0.f);
                rmin[mi][r] = fminf(rmin[mi][r], d2);
                cmin[mj]    = fminf(cmin[mj], d2);
            }

    #pragma unroll
    for (int m = 1; m < 16; m <<= 1)
        #pragma unroll
        for (int mi = 0; mi < 4; mi++)
            #pragma unroll
            for (int r = 0; r < 4; r++)
                rmin[mi][r] = fminf(rmin[mi][r], __shfl_xor(rmin[mi][r], m, 64));
    if (tx == 0) {
        #pragma unroll
        for (int mi = 0; mi < 4; mi++)
            #pragma unroll
            for (int r = 0; r < 4; r++)
                atomicMin(&rowmin[rbase + mi * 16 + quad * 4 + r], __float_as_uint(rmin[mi][r]));
    }
    #pragma unroll
    for (int m = 16; m < 64; m <<= 1)
        #pragma unroll
        for (int mj = 0; mj < 4; mj++)
            cmin[mj] = fminf(cmin[mj], __shfl_xor(cmin[mj], m, 64));
    if (quad == 0) {
        #pragma unroll
        for (int mj = 0; mj < 4; mj++)
            atomicMin(&colmin[cbase + mj * 16 + tx], __float_as_uint(cmin[mj]));
    }
}

// ---- Kernel 3: per-bc max over row/col mins, sqrt, mean over bc ----
__global__ __launch_bounds__(256) void finalize_kernel(const unsigned* __restrict__ rowmin,
                                                       const unsigned* __restrict__ colmin,
                                                       float* __restrict__ out) {
    int bc = blockIdx.x;
    float v = 0.f;
    for (int i = threadIdx.x; i < N; i += 256) {
        v = fmaxf(v, __uint_as_float(rowmin[bc * N + i]));
        v = fmaxf(v, __uint_as_float(colmin[bc * N + i]));
    }
    #pragma unroll
    for (int m = 1; m < 64; m <<= 1) v = fmaxf(v, __shfl_xor(v, m, 64));
    __shared__ float ws[4];
    int lane = threadIdx.x & 63, w = threadIdx.x >> 6;
    if (lane == 0) ws[w] = v;
    __syncthreads();
    if (threadIdx.x == 0) {
        float m = fmaxf(fmaxf(ws[0], ws[1]), fmaxf(ws[2], ws[3]));
        atomicAdd(out, sqrtf(m) * (1.0f / (float)BC));
    }
}

extern "C" void kernel_launch(void* const* d_in, const int* in_sizes, int n_in,
                              void* d_out, int out_size, void* d_ws, size_t ws_size,
                              hipStream_t stream) {
    const float* X = (const float*)d_in[0];   // input  [8,3,1024,1024]
    const float* Y = (const float*)d_in[1];   // target [8,3,1024,1024]
    float* out = (float*)d_out;               // scalar

    // ws layout: rowmin[24K u32] | colmin[24K u32] | xn[24K f32] | yn[24K f32] | Xf8 | Yf8
    unsigned* rowmin = (unsigned*)d_ws;
    unsigned* colmin = rowmin + BC * N;
    float* xn = (float*)(colmin + BC * N);
    float* yn = xn + BC * N;
    size_t head = (size_t)4 * BC * N * 4;            // 384 KB
    size_t f8_bytes = (size_t)BC * N * D;            // 25.17 MB each

    hipMemsetAsync(d_ws, 0xFF, (size_t)2 * BC * N * 4, stream);   // rowmin/colmin = +inf bits
    hipMemsetAsync(d_out, 0, sizeof(float), stream);
    // xn/yn need no memset: both prep paths fully overwrite every norm (plain stores).

    // ws_size is constant across calls, so this branch is graph-capture safe.
    if (ws_size >= head + 2 * f8_bytes) {
        unsigned char* Xf8 = (unsigned char*)d_ws + head;
        unsigned char* Yf8 = Xf8 + f8_bytes;
        prep_kernel<<<3072, 256, 0, stream>>>(X, Y, Xf8, Yf8, xn, yn);
        tile_f8_kernel<<<1536, 256, 0, stream>>>(Xf8, Yf8, xn, yn, rowmin, colmin);
    } else {
        dim3 grid(N / TILE, N / TILE, BC);
        norms_kernel<<<2 * BC * N / 4, 256, 0, stream>>>(X, Y, xn, yn);
        tile_conv_kernel<<<grid, 256, 0, stream>>>(X, Y, xn, yn, rowmin, colmin);
    }
    finalize_kernel<<<BC, 256, 0, stream>>>(rowmin, colmin, out);
}